// Round 1
// baseline (848.432 us; speedup 1.0000x reference)
//
#include <hip/hip_runtime.h>
#include <math.h>

#define B_ 1024
#define N_ 64
#define F_ 512

// ---------------------------------------------------------------------------
// Kernel 1: Wh[b] = h[b] (64x512) @ W (512x512), fp32.
// Grid (2, B): blockIdx.x = column half (256 cols), blockIdx.y = batch.
// Block 256 threads; each thread owns a 4row x 16col micro-tile (64 acc regs).
// ---------------------------------------------------------------------------
__global__ __launch_bounds__(256) void k_wh(const float* __restrict__ h,
                                            const float* __restrict__ W,
                                            float* __restrict__ Wh) {
  __shared__ float hs[64][36];    // 64 rows x 32 k (pad 36: 2-way max on row reads)
  __shared__ float ws[32][256];   // 32 k x 256 cols
  const int b  = blockIdx.y;
  const int gh = blockIdx.x;      // column half
  const int t  = threadIdx.x;
  const int tc = t & 15;          // col lane group
  const int tn = t >> 4;          // row group 0..15 -> rows tn*4..+3

  float acc[4][4][4];             // [r][q][c]: row tn*4+r, col q*64+tc*4+c
#pragma unroll
  for (int r = 0; r < 4; ++r)
#pragma unroll
    for (int q = 0; q < 4; ++q)
#pragma unroll
      for (int c = 0; c < 4; ++c) acc[r][q][c] = 0.f;

  const float* hb = h + (size_t)b * N_ * F_;

  for (int k0 = 0; k0 < F_; k0 += 32) {
    // stage h tile: 64x32 = 512 float4
#pragma unroll
    for (int i = 0; i < 2; ++i) {
      int id = t + 256 * i;
      int r = id >> 3, c4 = id & 7;
      float4 v = *(const float4*)(hb + r * F_ + k0 + c4 * 4);
      *(float4*)(&hs[r][c4 * 4]) = v;
    }
    // stage W tile: 32x256 = 2048 float4
#pragma unroll
    for (int i = 0; i < 8; ++i) {
      int id = t + 256 * i;
      int r = id >> 6, c4 = id & 63;
      float4 v = *(const float4*)(W + (size_t)(k0 + r) * F_ + gh * 256 + c4 * 4);
      *(float4*)(&ws[r][c4 * 4]) = v;
    }
    __syncthreads();

#pragma unroll
    for (int k = 0; k < 32; k += 4) {
      float4 a4[4];
#pragma unroll
      for (int r = 0; r < 4; ++r) a4[r] = *(const float4*)(&hs[tn * 4 + r][k]);
      float av[4][4];
#pragma unroll
      for (int r = 0; r < 4; ++r) {
        av[r][0] = a4[r].x; av[r][1] = a4[r].y; av[r][2] = a4[r].z; av[r][3] = a4[r].w;
      }
#pragma unroll
      for (int kk = 0; kk < 4; ++kk) {
        float4 bq[4];
#pragma unroll
        for (int q = 0; q < 4; ++q)
          bq[q] = *(const float4*)(&ws[k + kk][q * 64 + tc * 4]);
#pragma unroll
        for (int r = 0; r < 4; ++r) {
          float a = av[r][kk];
#pragma unroll
          for (int q = 0; q < 4; ++q) {
            acc[r][q][0] += a * bq[q].x;
            acc[r][q][1] += a * bq[q].y;
            acc[r][q][2] += a * bq[q].z;
            acc[r][q][3] += a * bq[q].w;
          }
        }
      }
    }
    __syncthreads();
  }

  float* whb = Wh + (size_t)b * N_ * F_;
#pragma unroll
  for (int r = 0; r < 4; ++r)
#pragma unroll
    for (int q = 0; q < 4; ++q) {
      float4 v = make_float4(acc[r][q][0], acc[r][q][1], acc[r][q][2], acc[r][q][3]);
      *(float4*)(whb + (tn * 4 + r) * F_ + gh * 256 + q * 64 + tc * 4) = v;
    }
}

// ---------------------------------------------------------------------------
// Kernel 2: per-batch pipeline. Grid = B blocks, 256 threads.
// LDS pool (floats):
//   e_s    [0,     4160)  stride 65   (e -> masked scores -> attention; lives to end)
//   hid_s  [4160,  8256)  stride 64   (MLP hidden chunk)
//   xm_s   [4160,  8512)  stride 68   (centered Wh chunk; dead before hid_s born)
//   a_s    [8512, 12608)  stride 64   (A1 chunk, then A2 chunk)
//   wh_s   [4160, 12352)  stride 128  (raw Wh chunk for h' GEMM; hid_s/a_s dead)
//   mu     [12608,12672), nrm [12672,12736)
// ---------------------------------------------------------------------------
__global__ __launch_bounds__(256) void k_attn(const float* __restrict__ Wh,
                                              const float* __restrict__ A1,
                                              const float* __restrict__ A2,
                                              const float* __restrict__ betap,
                                              float* __restrict__ out) {
  __shared__ float sm[12736];
  float* e_s   = sm;
  float* hid_s = sm + 4160;
  float* xm_s  = sm + 4160;
  float* a_s   = sm + 8512;
  float* wh_s  = sm + 4160;
  float* mu    = sm + 12608;
  float* nrm   = sm + 12672;

  const int b = blockIdx.x;
  const int t = threadIdx.x;
  const float beta = betap[0];
  const float* whb = Wh + (size_t)b * N_ * F_;

  // ---- row means of Wh[b] ----
  {
    int n = t >> 2, q = t & 3;
    const float* row = whb + n * F_ + q * 128;
    float s = 0.f;
#pragma unroll
    for (int i = 0; i < 32; ++i) {
      float4 v = *(const float4*)(row + i * 4);
      s += v.x + v.y + v.z + v.w;
    }
    s += __shfl_xor(s, 1);
    s += __shfl_xor(s, 2);
    if (q == 0) mu[n] = s * (1.f / F_);
  }
  __syncthreads();

  // ---- cov: thread owns pairs (n = tn+16r, m = tm+16c), 4x4 ----
  const int tm = t & 15, tn = t >> 4;
  float cov[4][4];
#pragma unroll
  for (int r = 0; r < 4; ++r)
#pragma unroll
    for (int c = 0; c < 4; ++c) cov[r][c] = 0.f;

  for (int ch = 0; ch < 8; ++ch) {
    // stage centered 64x64 chunk
#pragma unroll
    for (int i = 0; i < 4; ++i) {
      int id = t + 256 * i;
      int r = id >> 4, c4 = id & 15;
      float4 v = *(const float4*)(whb + r * F_ + ch * 64 + c4 * 4);
      float m_ = mu[r];
      v.x -= m_; v.y -= m_; v.z -= m_; v.w -= m_;
      *(float4*)(&xm_s[r * 68 + c4 * 4]) = v;
    }
    __syncthreads();
#pragma unroll
    for (int f0 = 0; f0 < 64; f0 += 4) {
      float4 xa[4], xb[4];
#pragma unroll
      for (int r = 0; r < 4; ++r) xa[r] = *(const float4*)(&xm_s[(tn + 16 * r) * 68 + f0]);
#pragma unroll
      for (int c = 0; c < 4; ++c) xb[c] = *(const float4*)(&xm_s[(tm + 16 * c) * 68 + f0]);
#pragma unroll
      for (int r = 0; r < 4; ++r)
#pragma unroll
        for (int c = 0; c < 4; ++c)
          cov[r][c] += xa[r].x * xb[c].x + xa[r].y * xb[c].y +
                       xa[r].z * xb[c].z + xa[r].w * xb[c].w;
    }
    __syncthreads();
  }

  // norms from diagonal pairs
  if (tn == tm) {
#pragma unroll
    for (int r = 0; r < 4; ++r) nrm[tn + 16 * r] = sqrtf(cov[r][r]);
  }
  __syncthreads();

  // e = beta * |cov / (nrm_n*nrm_m + EPS)|
#pragma unroll
  for (int r = 0; r < 4; ++r) {
    int n = tn + 16 * r;
#pragma unroll
    for (int c = 0; c < 4; ++c) {
      int m = tm + 16 * c;
      float denom = nrm[n] * nrm[m] + 1e-8f;
      e_s[n * 65 + m] = beta * fabsf(cov[r][c] / denom);
    }
  }
  __syncthreads();

  // ---- MLP: hidden = relu(e @ A1); adjp = hidden @ A2 (K=256 in 4 chunks) ----
  float adjp[4][4];
#pragma unroll
  for (int r = 0; r < 4; ++r)
#pragma unroll
    for (int c = 0; c < 4; ++c) adjp[r][c] = 0.f;

  const int rg = t >> 4;   // layer1 rows rg*4..+3
  const int jg = t & 15;   // layer1 cols jg*4..+3

  for (int kc = 0; kc < 4; ++kc) {
    // stage A1 chunk: a_s[m*64 + j] = A1[m][kc*64 + j]
#pragma unroll
    for (int i = 0; i < 4; ++i) {
      int id = t + 256 * i;
      int m = id >> 4, c4 = id & 15;
      *(float4*)(&a_s[m * 64 + c4 * 4]) =
          *(const float4*)(A1 + (size_t)m * 256 + kc * 64 + c4 * 4);
    }
    __syncthreads();

    // layer1: hid[n][j], n = rg*4+rr, j = jg*4+jj
    float h1[4][4];
#pragma unroll
    for (int rr = 0; rr < 4; ++rr)
#pragma unroll
      for (int jj = 0; jj < 4; ++jj) h1[rr][jj] = 0.f;
    for (int m = 0; m < 64; ++m) {
      float er[4];
#pragma unroll
      for (int rr = 0; rr < 4; ++rr) er[rr] = e_s[(rg * 4 + rr) * 65 + m];
      float4 a4 = *(const float4*)(&a_s[m * 64 + jg * 4]);
#pragma unroll
      for (int rr = 0; rr < 4; ++rr) {
        h1[rr][0] += er[rr] * a4.x;
        h1[rr][1] += er[rr] * a4.y;
        h1[rr][2] += er[rr] * a4.z;
        h1[rr][3] += er[rr] * a4.w;
      }
    }
#pragma unroll
    for (int rr = 0; rr < 4; ++rr) {
      float4 v = make_float4(fmaxf(h1[rr][0], 0.f), fmaxf(h1[rr][1], 0.f),
                             fmaxf(h1[rr][2], 0.f), fmaxf(h1[rr][3], 0.f));
      *(float4*)(&hid_s[(rg * 4 + rr) * 64 + jg * 4]) = v;
    }
    __syncthreads();

    // stage A2 chunk: a_s[j*64 + m] = A2[kc*64+j][m]
#pragma unroll
    for (int i = 0; i < 4; ++i) {
      int id = t + 256 * i;
      int j = id >> 4, c4 = id & 15;
      *(float4*)(&a_s[j * 64 + c4 * 4]) =
          *(const float4*)(A2 + (size_t)(kc * 64 + j) * 64 + c4 * 4);
    }
    __syncthreads();

    // layer2: adjp[r][c], n = tn*4+r, m = tm*4+c
#pragma unroll
    for (int j0 = 0; j0 < 64; j0 += 4) {
      float4 hr[4], a2v[4];
#pragma unroll
      for (int r = 0; r < 4; ++r) hr[r] = *(const float4*)(&hid_s[(tn * 4 + r) * 64 + j0]);
#pragma unroll
      for (int jj = 0; jj < 4; ++jj) a2v[jj] = *(const float4*)(&a_s[(j0 + jj) * 64 + tm * 4]);
#pragma unroll
      for (int r = 0; r < 4; ++r) {
        float hv[4] = {hr[r].x, hr[r].y, hr[r].z, hr[r].w};
#pragma unroll
        for (int jj = 0; jj < 4; ++jj) {
          adjp[r][0] += hv[jj] * a2v[jj].x;
          adjp[r][1] += hv[jj] * a2v[jj].y;
          adjp[r][2] += hv[jj] * a2v[jj].z;
          adjp[r][3] += hv[jj] * a2v[jj].w;
        }
      }
    }
    __syncthreads();
  }

  // mask: s = (e + mlp) > 0 ? e : NEG, in place on e_s
#pragma unroll
  for (int r = 0; r < 4; ++r) {
    int n = tn * 4 + r;
#pragma unroll
    for (int c = 0; c < 4; ++c) {
      int m = tm * 4 + c;
      float ev = e_s[n * 65 + m];
      float pre = ev + adjp[r][c];
      e_s[n * 65 + m] = (pre > 0.f) ? ev : -1e12f;
    }
  }
  __syncthreads();

  // ---- softmax per row, 4 lanes/row ----
  {
    int n = t >> 2, p = t & 3;
    float mx = -3.0e38f;
#pragma unroll
    for (int i = 0; i < 16; ++i) mx = fmaxf(mx, e_s[n * 65 + p * 16 + i]);
    mx = fmaxf(mx, __shfl_xor(mx, 1));
    mx = fmaxf(mx, __shfl_xor(mx, 2));
    float ev[16];
    float ssum = 0.f;
#pragma unroll
    for (int i = 0; i < 16; ++i) {
      ev[i] = expf(e_s[n * 65 + p * 16 + i] - mx);
      ssum += ev[i];
    }
    ssum += __shfl_xor(ssum, 1);
    ssum += __shfl_xor(ssum, 2);
    float inv = 1.f / ssum;
#pragma unroll
    for (int i = 0; i < 16; ++i) e_s[n * 65 + p * 16 + i] = ev[i] * inv;
  }
  __syncthreads();

  // ---- h' = attention @ Wh: 4 chunks of 128 cols ----
  const int jf  = t & 31;   // float4 index in chunk
  const int rg2 = t >> 5;   // rows rg2*8..+7
  for (int ch = 0; ch < 4; ++ch) {
#pragma unroll
    for (int i = 0; i < 8; ++i) {
      int id = t + 256 * i;
      int r = id >> 5, c4 = id & 31;
      *(float4*)(&wh_s[r * 128 + c4 * 4]) =
          *(const float4*)(whb + r * F_ + ch * 128 + c4 * 4);
    }
    __syncthreads();
    float4 acc[8];
#pragma unroll
    for (int rr = 0; rr < 8; ++rr) acc[rr] = make_float4(0.f, 0.f, 0.f, 0.f);
    for (int m = 0; m < 64; ++m) {
      float4 wv = *(const float4*)(&wh_s[m * 128 + jf * 4]);
#pragma unroll
      for (int rr = 0; rr < 8; ++rr) {
        float a = e_s[(rg2 * 8 + rr) * 65 + m];
        acc[rr].x += a * wv.x;
        acc[rr].y += a * wv.y;
        acc[rr].z += a * wv.z;
        acc[rr].w += a * wv.w;
      }
    }
    float* ob = out + (size_t)b * N_ * F_ + ch * 128;
#pragma unroll
    for (int rr = 0; rr < 8; ++rr)
      *(float4*)(ob + (rg2 * 8 + rr) * F_ + jf * 4) = acc[rr];
    __syncthreads();
  }
}

extern "C" void kernel_launch(void* const* d_in, const int* in_sizes, int n_in,
                              void* d_out, int out_size, void* d_ws, size_t ws_size,
                              hipStream_t stream) {
  const float* h    = (const float*)d_in[0];
  const float* W    = (const float*)d_in[1];
  const float* beta = (const float*)d_in[2];
  const float* A1   = (const float*)d_in[3];
  const float* A2   = (const float*)d_in[4];
  float* out = (float*)d_out;
  float* Wh  = (float*)d_ws;  // needs B*N*F*4 = 128 MiB of workspace

  k_wh<<<dim3(2, B_), 256, 0, stream>>>(h, W, Wh);
  k_attn<<<B_, 256, 0, stream>>>(Wh, A1, A2, beta, out);
}